// Round 3
// baseline (213.526 us; speedup 1.0000x reference)
//
#include <hip/hip_runtime.h>

// 1 - alpha = (1 + exp(density+shift))^(-0.5) = rsqrt(u), u = 1 + exp(x).
// alpha * (1/(1-alpha)) = u*a - 1, so w = T_excl * alpha.

__device__ __forceinline__ float fast_sigmoid(float x) {
    return __builtin_amdgcn_rcpf(1.0f + __expf(-x));
}

// ---- DPP wave64 scans ------------------------------------------------------
#define DPP_ADD(x, ctrl, rmask)                                               \
    do {                                                                      \
        int _s = __builtin_amdgcn_update_dpp(0, __float_as_int(x), (ctrl),    \
                                             (rmask), 0xf, true);             \
        (x) += __int_as_float(_s);                                            \
    } while (0)

#define DPP_MUL(x, ctrl, rmask)                                               \
    do {                                                                      \
        int _s = __builtin_amdgcn_update_dpp(0x3f800000, __float_as_int(x),   \
                                             (ctrl), (rmask), 0xf, false);    \
        (x) *= __int_as_float(_s);                                            \
    } while (0)

__device__ __forceinline__ float wave_scan_add(float x) {
    DPP_ADD(x, 0x111, 0xf);  // row_shr:1
    DPP_ADD(x, 0x112, 0xf);  // row_shr:2
    DPP_ADD(x, 0x114, 0xf);  // row_shr:4
    DPP_ADD(x, 0x118, 0xf);  // row_shr:8
    DPP_ADD(x, 0x142, 0xa);  // row_bcast:15 -> rows 1,3
    DPP_ADD(x, 0x143, 0xc);  // row_bcast:31 -> rows 2,3
    return x;
}

// Full-wave inclusive product scan.
__device__ __forceinline__ float wave_scan_mul(float x) {
    DPP_MUL(x, 0x111, 0xf);
    DPP_MUL(x, 0x112, 0xf);
    DPP_MUL(x, 0x114, 0xf);
    DPP_MUL(x, 0x118, 0xf);
    DPP_MUL(x, 0x142, 0xa);
    DPP_MUL(x, 0x143, 0xc);
    return x;
}

// Inclusive product scan SEGMENTED at the lane-31/32 boundary: the first five
// DPP stages never cross 32-lane halves; dropping row_bcast:31 keeps the two
// halves independent. Totals live in lanes 31 and 63.
__device__ __forceinline__ float wave_scan_mul_half(float x) {
    DPP_MUL(x, 0x111, 0xf);
    DPP_MUL(x, 0x112, 0xf);
    DPP_MUL(x, 0x114, 0xf);
    DPP_MUL(x, 0x118, 0xf);
    DPP_MUL(x, 0x142, 0xa);
    return x;
}

__device__ __forceinline__ float bcast_lane63(float x) {
    return __int_as_float(__builtin_amdgcn_readlane(__float_as_int(x), 63));
}
__device__ __forceinline__ float bcast_lane31(float x) {
    return __int_as_float(__builtin_amdgcn_readlane(__float_as_int(x), 31));
}

// ---- Pass 1: segment starts (int4-vectorized boundary detection) -----------
__global__ __launch_bounds__(256) void seg_starts4_kernel(
    const int4* __restrict__ ray4, int M4, int M, int N,
    const int* __restrict__ ray_id, int* __restrict__ starts)
{
    const int i = blockIdx.x * blockDim.x + threadIdx.x;
    if (i >= M4) return;
    const int4 v = ray4[i];
    const int prev = (i == 0) ? -1 : ray_id[4 * i - 1];
    const int base = 4 * i;
    for (int r = prev + 1; r <= v.x; ++r) starts[r] = base;
    for (int r = v.x + 1;  r <= v.y; ++r) starts[r] = base + 1;
    for (int r = v.y + 1;  r <= v.z; ++r) starts[r] = base + 2;
    for (int r = v.z + 1;  r <= v.w; ++r) starts[r] = base + 3;
    if (i == M4 - 1) {
        int last = v.w;
        for (int j = 4 * M4; j < M; ++j) {      // scalar tail (M%4)
            const int cur = ray_id[j];
            for (int r = last + 1; r <= cur; ++r) starts[r] = j;
            last = cur;
        }
        for (int r = last + 1; r <= N; ++r) starts[r] = M;
    }
}

// ---- Pass 2: RPW rays per wave, paired-overflow chunks ----------------------
// Ray lengths ~ Poisson(64): chunk-0 is ~92% lane-utilized, but the overflow
// (len-64) averages only ~6 samples and is <=32 for essentially every ray
// (len>96 is ~4 rays in 131072). So overflows of ray PAIRS are packed into
// one wave: ray 2p in lanes 0-31, ray 2p+1 in lanes 32-63, scanned with the
// half-segmented DPP scan. Chunk work per wave: 8 -> 6 (-25% VALU), loads
// 32 -> 24, with the SAME branchless straight-line structure as the best
// known build (R2's uniform branches serialized the DPP chains and lost).
// Rare len>96 rays fall back to a uniform-branch full-wave loop.
#define RPW 4
#define NPAIR (RPW / 2)

__global__ __launch_bounds__(256, 4) void favor_render_kernel(
    const float* __restrict__ density,
    const float* __restrict__ rgb_feat,   // [M,3]
    const float* __restrict__ shift,      // [1]
    const int*   __restrict__ starts,     // [N+1]
    int M, int N,
    float* __restrict__ weights,          // [M]
    float* __restrict__ alphainv_last,    // [N]
    float* __restrict__ out3)             // [N,3]
{
    const int wave = (blockIdx.x * blockDim.x + threadIdx.x) >> 6;
    const int t    = threadIdx.x & 63;
    const int r0   = wave * RPW;
    if (r0 >= N) return;

    // Bounds for all RPW rays: one coalesced load, broadcast to SGPRs.
    const int bv = starts[min(r0 + t, N)];
    int s[RPW + 1];
    #pragma unroll
    for (int k = 0; k <= RPW; ++k)
        s[k] = __builtin_amdgcn_readlane(bv, k);

    const float sh = shift[0];
    const bool lowHalf = t < 32;

    // ---- Phase A: issue ALL loads up front (chunk0 x4, paired overflow x2) --
    float d0[RPW], r0v[RPW], g0v[RPW], b0v[RPW];
    #pragma unroll
    for (int j = 0; j < RPW; ++j) {
        const int st = s[j], en = s[j + 1];
        const int c0 = max(min(st + t, en - 1), 0);
        d0[j]  = density[c0];
        r0v[j] = rgb_feat[3 * c0 + 0];
        g0v[j] = rgb_feat[3 * c0 + 1];
        b0v[j] = rgb_feat[3 * c0 + 2];
    }
    float dP[NPAIR], rP[NPAIR], gP[NPAIR], bP[NPAIR];
    int   iP[NPAIR];
    #pragma unroll
    for (int p = 0; p < NPAIR; ++p) {
        // lane t<32: ray 2p sample st+64+t; lane t>=32: ray 2p+1 sample
        // st+64+(t-32) = st+32+t.
        const int idx = lowHalf ? (s[2 * p] + 64 + t) : (s[2 * p + 1] + 32 + t);
        const int en  = lowHalf ? s[2 * p + 1] : s[2 * p + 2];
        iP[p] = idx;
        const int c = max(min(idx, en - 1), 0);   // short ray -> clamped bcast
        dP[p] = density[c];
        rP[p] = rgb_feat[3 * c + 0];
        gP[p] = rgb_feat[3 * c + 1];
        bP[p] = rgb_feat[3 * c + 2];
    }

    float carryT[RPW], accR[RPW], accG[RPW], accB[RPW];

    // ---- Phase B: chunk-0 of all rays (4 independent chains, full ILP) ----
    #pragma unroll
    for (int j = 0; j < RPW; ++j) {
        const int st = s[j], en = s[j + 1];
        const bool valid = (st + t) < en;
        const float u = 1.0f + __expf(d0[j] + sh);
        const float a = __builtin_amdgcn_rsqf(u);      // 1 - alpha
        const float m = valid ? a : 1.0f;
        const float S = wave_scan_mul(m);              // inclusive product
        carryT[j] = bcast_lane63(S);
        const float w = S * (u * a - 1.0f);            // T_excl * alpha
        accR[j] = valid ? w * fast_sigmoid(r0v[j]) : 0.0f;
        accG[j] = valid ? w * fast_sigmoid(g0v[j]) : 0.0f;
        accB[j] = valid ? w * fast_sigmoid(b0v[j]) : 0.0f;
        if (valid) weights[st + t] = w;
    }

    // ---- Phase C: paired overflow chunks (2 independent chains, branchless) -
    #pragma unroll
    for (int p = 0; p < NPAIR; ++p) {
        const int jA = 2 * p, jB = 2 * p + 1;
        const int en  = lowHalf ? s[jA + 1] : s[jB + 1];
        const int idx = iP[p];
        const bool valid = idx < en;
        const float u = 1.0f + __expf(dP[p] + sh);
        const float a = __builtin_amdgcn_rsqf(u);
        const float m = valid ? a : 1.0f;
        const float S = wave_scan_mul_half(m);         // segmented at lane 32
        const float totA = bcast_lane31(S);
        const float totB = bcast_lane63(S);
        const float carrySel = lowHalf ? carryT[jA] : carryT[jB];
        const float w = carrySel * S * (u * a - 1.0f);
        const float cR = valid ? w * fast_sigmoid(rP[p]) : 0.0f;
        const float cG = valid ? w * fast_sigmoid(gP[p]) : 0.0f;
        const float cB = valid ? w * fast_sigmoid(bP[p]) : 0.0f;
        accR[jA] += lowHalf ? cR : 0.0f;
        accG[jA] += lowHalf ? cG : 0.0f;
        accB[jA] += lowHalf ? cB : 0.0f;
        accR[jB] += lowHalf ? 0.0f : cR;
        accG[jB] += lowHalf ? 0.0f : cG;
        accB[jB] += lowHalf ? 0.0f : cB;
        if (valid) weights[idx] = w;
        carryT[jA] *= totA;
        carryT[jB] *= totB;
    }

    // ---- Phase D: len > 96 fallback (uniform branch; ~4 rays in 131072) ----
    #pragma unroll
    for (int j = 0; j < RPW; ++j) {
        const int st = s[j], en = s[j + 1];
        if (en - st > 96) {
            for (int base = st + 96; base < en; base += 64) {
                const int i = base + t;
                const bool v2 = i < en;
                const int c = min(i, en - 1);
                const float dd = density[c];
                const float rr = rgb_feat[3 * c + 0];
                const float gg = rgb_feat[3 * c + 1];
                const float bb = rgb_feat[3 * c + 2];
                const float u2 = 1.0f + __expf(dd + sh);
                const float a2 = __builtin_amdgcn_rsqf(u2);
                const float m2 = v2 ? a2 : 1.0f;
                const float S2 = wave_scan_mul(m2);
                const float tot2 = bcast_lane63(S2);
                const float w2 = carryT[j] * S2 * (u2 * a2 - 1.0f);
                if (v2) {
                    weights[i] = w2;
                    accR[j] += w2 * fast_sigmoid(rr);
                    accG[j] += w2 * fast_sigmoid(gg);
                    accB[j] += w2 * fast_sigmoid(bb);
                }
                carryT[j] *= tot2;
            }
        }
    }

    // ---- Phase E: epilogue — 12 independent DPP reduce chains, batched ----
    float tR[RPW], tG[RPW], tB[RPW];
    #pragma unroll
    for (int j = 0; j < RPW; ++j) {
        tR[j] = wave_scan_add(accR[j]);
        tG[j] = wave_scan_add(accG[j]);
        tB[j] = wave_scan_add(accB[j]);
    }
    #pragma unroll
    for (int j = 0; j < RPW; ++j) {
        const float sR = bcast_lane63(tR[j]);
        const float sG = bcast_lane63(tG[j]);
        const float sB = bcast_lane63(tB[j]);
        const int ray = r0 + j;
        if (t == 0 && ray < N) {
            alphainv_last[ray] = carryT[j];
            out3[3 * ray + 0] = sR + carryT[j];
            out3[3 * ray + 1] = sG + carryT[j];
            out3[3 * ray + 2] = sB + carryT[j];
        }
    }
}

extern "C" void kernel_launch(void* const* d_in, const int* in_sizes, int n_in,
                              void* d_out, int out_size, void* d_ws, size_t ws_size,
                              hipStream_t stream) {
    const float* density  = (const float*)d_in[0];
    const float* rgb_feat = (const float*)d_in[1];
    const float* shift    = (const float*)d_in[2];
    const int*   ray_id   = (const int*)d_in[3];

    const int M = in_sizes[0];
    const int N = (out_size - M) / 4;   // out_size = M + N + 3N

    float* weights       = (float*)d_out;
    float* alphainv_last = weights + M;
    float* out3          = alphainv_last + N;

    const int block = 256;
    int* starts = (int*)d_ws;

    const int M4 = M >> 2;
    const int grid_starts = (M4 + block - 1) / block;
    seg_starts4_kernel<<<grid_starts, block, 0, stream>>>(
        (const int4*)ray_id, M4, M, N, ray_id, starts);

    const int n_waves = (N + RPW - 1) / RPW;
    const int grid_render = (n_waves * 64 + block - 1) / block;
    favor_render_kernel<<<grid_render, block, 0, stream>>>(
        density, rgb_feat, shift, starts, M, N,
        weights, alphainv_last, out3);
}

// Round 5
// 211.814 us; speedup vs baseline: 1.0081x; 1.0081x over previous
//
#include <hip/hip_runtime.h>

// 1 - alpha = (1 + exp(density+shift))^(-0.5) = rsqrt(u), u = 1 + exp(x).
// alpha * (1/(1-alpha)) = u*a - 1, so w = T_excl * alpha.

__device__ __forceinline__ float fast_sigmoid(float x) {
    return __builtin_amdgcn_rcpf(1.0f + __expf(-x));
}

struct __align__(4) f3 { float x, y, z; };   // 12B, 4B-aligned -> dwordx3

// ---- DPP wave64 scans ------------------------------------------------------
#define DPP_ADD(x, ctrl, rmask)                                               \
    do {                                                                      \
        int _s = __builtin_amdgcn_update_dpp(0, __float_as_int(x), (ctrl),    \
                                             (rmask), 0xf, true);             \
        (x) += __int_as_float(_s);                                            \
    } while (0)

#define DPP_MUL(x, ctrl, rmask)                                               \
    do {                                                                      \
        int _s = __builtin_amdgcn_update_dpp(0x3f800000, __float_as_int(x),   \
                                             (ctrl), (rmask), 0xf, false);    \
        (x) *= __int_as_float(_s);                                            \
    } while (0)

__device__ __forceinline__ float wave_scan_add(float x) {
    DPP_ADD(x, 0x111, 0xf);  // row_shr:1
    DPP_ADD(x, 0x112, 0xf);  // row_shr:2
    DPP_ADD(x, 0x114, 0xf);  // row_shr:4
    DPP_ADD(x, 0x118, 0xf);  // row_shr:8
    DPP_ADD(x, 0x142, 0xa);  // row_bcast:15 -> rows 1,3
    DPP_ADD(x, 0x143, 0xc);  // row_bcast:31 -> rows 2,3
    return x;
}

// Full-wave inclusive product scan.
__device__ __forceinline__ float wave_scan_mul(float x) {
    DPP_MUL(x, 0x111, 0xf);
    DPP_MUL(x, 0x112, 0xf);
    DPP_MUL(x, 0x114, 0xf);
    DPP_MUL(x, 0x118, 0xf);
    DPP_MUL(x, 0x142, 0xa);
    DPP_MUL(x, 0x143, 0xc);
    return x;
}

// Inclusive product scan SEGMENTED at the lane-31/32 boundary (first five DPP
// stages never cross 32-lane halves). Totals live in lanes 31 and 63.
__device__ __forceinline__ float wave_scan_mul_half(float x) {
    DPP_MUL(x, 0x111, 0xf);
    DPP_MUL(x, 0x112, 0xf);
    DPP_MUL(x, 0x114, 0xf);
    DPP_MUL(x, 0x118, 0xf);
    DPP_MUL(x, 0x142, 0xa);
    return x;
}

__device__ __forceinline__ float bcast_lane63(float x) {
    return __int_as_float(__builtin_amdgcn_readlane(__float_as_int(x), 63));
}
__device__ __forceinline__ float bcast_lane31(float x) {
    return __int_as_float(__builtin_amdgcn_readlane(__float_as_int(x), 31));
}

// ---- Pass 1: segment starts (int4-vectorized boundary detection) -----------
__global__ __launch_bounds__(256) void seg_starts4_kernel(
    const int4* __restrict__ ray4, int M4, int M, int N,
    const int* __restrict__ ray_id, int* __restrict__ starts)
{
    const int i = blockIdx.x * blockDim.x + threadIdx.x;
    if (i >= M4) return;
    const int4 v = ray4[i];
    const int prev = (i == 0) ? -1 : ray_id[4 * i - 1];
    const int base = 4 * i;
    for (int r = prev + 1; r <= v.x; ++r) starts[r] = base;
    for (int r = v.x + 1;  r <= v.y; ++r) starts[r] = base + 1;
    for (int r = v.y + 1;  r <= v.z; ++r) starts[r] = base + 2;
    for (int r = v.z + 1;  r <= v.w; ++r) starts[r] = base + 3;
    if (i == M4 - 1) {
        int last = v.w;
        for (int j = 4 * M4; j < M; ++j) {      // scalar tail (M%4)
            const int cur = ray_id[j];
            for (int r = last + 1; r <= cur; ++r) starts[r] = j;
            last = cur;
        }
        for (int r = last + 1; r <= N; ++r) starts[r] = M;
    }
}

// ---- Pass 2: RPW rays per wave, paired-overflow chunks, PINNED prefetch ----
// Three rounds of evidence: time is invariant to VALU-work reduction and
// VGPR stays ~28 -> the compiler sinks the prefetch loads into the consuming
// phases (24 floats can't live in 28 VGPRs), so each wave pays ~6 full
// memory latencies serially. Fix: a single keep-alive asm consuming ALL 24
// loaded values forces simultaneous materialization -> loads cannot be sunk;
// one vmcnt(0) wait, then pure compute. rgb loads are dwordx3 (float3).
#define RPW 4
#define NPAIR (RPW / 2)

__global__ __launch_bounds__(256, 4) void favor_render_kernel(
    const float* __restrict__ density,
    const float* __restrict__ rgb_feat,   // [M,3]
    const float* __restrict__ shift,      // [1]
    const int*   __restrict__ starts,     // [N+1]
    int M, int N,
    float* __restrict__ weights,          // [M]
    float* __restrict__ alphainv_last,    // [N]
    float* __restrict__ out3)             // [N,3]
{
    const int wave = (blockIdx.x * blockDim.x + threadIdx.x) >> 6;
    const int t    = threadIdx.x & 63;
    const int r0   = wave * RPW;
    if (r0 >= N) return;

    // Bounds for all RPW rays: one coalesced load, broadcast to SGPRs.
    const int bv = starts[min(r0 + t, N)];
    int s[RPW + 1];
    #pragma unroll
    for (int k = 0; k <= RPW; ++k)
        s[k] = __builtin_amdgcn_readlane(bv, k);

    const float sh = shift[0];
    const bool lowHalf = t < 32;

    // ---- Phase A: issue ALL loads up front (chunk0 x4, paired overflow x2) --
    float d0[RPW];  f3 c0v[RPW];
    float dP[NPAIR]; f3 cPv[NPAIR];
    int   iP[NPAIR];
    #pragma unroll
    for (int j = 0; j < RPW; ++j) {
        const int st = s[j], en = s[j + 1];
        const int c0 = max(min(st + t, en - 1), 0);
        d0[j]  = density[c0];
        c0v[j] = *(const f3*)(rgb_feat + 3 * c0);
    }
    #pragma unroll
    for (int p = 0; p < NPAIR; ++p) {
        // lane t<32: ray 2p sample st+64+t; lane t>=32: ray 2p+1 sample
        // st+64+(t-32) = st+32+t.
        const int idx = lowHalf ? (s[2 * p] + 64 + t) : (s[2 * p + 1] + 32 + t);
        const int en  = lowHalf ? s[2 * p + 1] : s[2 * p + 2];
        iP[p] = idx;
        const int c = max(min(idx, en - 1), 0);   // short ray -> clamped bcast
        dP[p]  = density[c];
        cPv[p] = *(const f3*)(rgb_feat + 3 * c);
    }
    // Keep-alive pin: all 24 loaded values must be simultaneously live here.
    // The scheduler/regalloc cannot sink, split, or rematerialize the loads;
    // the wave pays ONE vmcnt(0) wait, then runs straight-line compute.
    __builtin_amdgcn_sched_barrier(0);
    asm volatile("" ::
        "v"(d0[0]), "v"(c0v[0].x), "v"(c0v[0].y), "v"(c0v[0].z),
        "v"(d0[1]), "v"(c0v[1].x), "v"(c0v[1].y), "v"(c0v[1].z),
        "v"(d0[2]), "v"(c0v[2].x), "v"(c0v[2].y), "v"(c0v[2].z),
        "v"(d0[3]), "v"(c0v[3].x), "v"(c0v[3].y), "v"(c0v[3].z),
        "v"(dP[0]), "v"(cPv[0].x), "v"(cPv[0].y), "v"(cPv[0].z),
        "v"(dP[1]), "v"(cPv[1].x), "v"(cPv[1].y), "v"(cPv[1].z));
    __builtin_amdgcn_sched_barrier(0);

    float carryT[RPW], accR[RPW], accG[RPW], accB[RPW];

    // ---- Phase B: chunk-0 of all rays (4 independent chains, full ILP) ----
    #pragma unroll
    for (int j = 0; j < RPW; ++j) {
        const int st = s[j], en = s[j + 1];
        const bool valid = (st + t) < en;
        const float u = 1.0f + __expf(d0[j] + sh);
        const float a = __builtin_amdgcn_rsqf(u);      // 1 - alpha
        const float m = valid ? a : 1.0f;
        const float S = wave_scan_mul(m);              // inclusive product
        carryT[j] = bcast_lane63(S);
        const float w = S * (u * a - 1.0f);            // T_excl * alpha
        accR[j] = valid ? w * fast_sigmoid(c0v[j].x) : 0.0f;
        accG[j] = valid ? w * fast_sigmoid(c0v[j].y) : 0.0f;
        accB[j] = valid ? w * fast_sigmoid(c0v[j].z) : 0.0f;
        if (valid) weights[st + t] = w;
    }

    // ---- Phase C: paired overflow chunks (2 independent chains, branchless) -
    #pragma unroll
    for (int p = 0; p < NPAIR; ++p) {
        const int jA = 2 * p, jB = 2 * p + 1;
        const int en  = lowHalf ? s[jA + 1] : s[jB + 1];
        const int idx = iP[p];
        const bool valid = idx < en;
        const float u = 1.0f + __expf(dP[p] + sh);
        const float a = __builtin_amdgcn_rsqf(u);
        const float m = valid ? a : 1.0f;
        const float S = wave_scan_mul_half(m);         // segmented at lane 32
        const float totA = bcast_lane31(S);
        const float totB = bcast_lane63(S);
        const float carrySel = lowHalf ? carryT[jA] : carryT[jB];
        const float w = carrySel * S * (u * a - 1.0f);
        const float cR = valid ? w * fast_sigmoid(cPv[p].x) : 0.0f;
        const float cG = valid ? w * fast_sigmoid(cPv[p].y) : 0.0f;
        const float cB = valid ? w * fast_sigmoid(cPv[p].z) : 0.0f;
        accR[jA] += lowHalf ? cR : 0.0f;
        accG[jA] += lowHalf ? cG : 0.0f;
        accB[jA] += lowHalf ? cB : 0.0f;
        accR[jB] += lowHalf ? 0.0f : cR;
        accG[jB] += lowHalf ? 0.0f : cG;
        accB[jB] += lowHalf ? 0.0f : cB;
        if (valid) weights[idx] = w;
        carryT[jA] *= totA;
        carryT[jB] *= totB;
    }

    // ---- Phase D: len > 96 fallback (uniform branch; ~4 rays in 131072) ----
    #pragma unroll
    for (int j = 0; j < RPW; ++j) {
        const int st = s[j], en = s[j + 1];
        if (en - st > 96) {
            for (int base = st + 96; base < en; base += 64) {
                const int i = base + t;
                const bool v2 = i < en;
                const int c = min(i, en - 1);
                const float dd = density[c];
                const f3 cc = *(const f3*)(rgb_feat + 3 * c);
                const float u2 = 1.0f + __expf(dd + sh);
                const float a2 = __builtin_amdgcn_rsqf(u2);
                const float m2 = v2 ? a2 : 1.0f;
                const float S2 = wave_scan_mul(m2);
                const float tot2 = bcast_lane63(S2);
                const float w2 = carryT[j] * S2 * (u2 * a2 - 1.0f);
                if (v2) {
                    weights[i] = w2;
                    accR[j] += w2 * fast_sigmoid(cc.x);
                    accG[j] += w2 * fast_sigmoid(cc.y);
                    accB[j] += w2 * fast_sigmoid(cc.z);
                }
                carryT[j] *= tot2;
            }
        }
    }

    // ---- Phase E: epilogue — 12 independent DPP reduce chains, batched ----
    float tR[RPW], tG[RPW], tB[RPW];
    #pragma unroll
    for (int j = 0; j < RPW; ++j) {
        tR[j] = wave_scan_add(accR[j]);
        tG[j] = wave_scan_add(accG[j]);
        tB[j] = wave_scan_add(accB[j]);
    }
    #pragma unroll
    for (int j = 0; j < RPW; ++j) {
        const float sR = bcast_lane63(tR[j]);
        const float sG = bcast_lane63(tG[j]);
        const float sB = bcast_lane63(tB[j]);
        const int ray = r0 + j;
        if (t == 0 && ray < N) {
            alphainv_last[ray] = carryT[j];
            out3[3 * ray + 0] = sR + carryT[j];
            out3[3 * ray + 1] = sG + carryT[j];
            out3[3 * ray + 2] = sB + carryT[j];
        }
    }
}

extern "C" void kernel_launch(void* const* d_in, const int* in_sizes, int n_in,
                              void* d_out, int out_size, void* d_ws, size_t ws_size,
                              hipStream_t stream) {
    const float* density  = (const float*)d_in[0];
    const float* rgb_feat = (const float*)d_in[1];
    const float* shift    = (const float*)d_in[2];
    const int*   ray_id   = (const int*)d_in[3];

    const int M = in_sizes[0];
    const int N = (out_size - M) / 4;   // out_size = M + N + 3N

    float* weights       = (float*)d_out;
    float* alphainv_last = weights + M;
    float* out3          = alphainv_last + N;

    const int block = 256;
    int* starts = (int*)d_ws;

    const int M4 = M >> 2;
    const int grid_starts = (M4 + block - 1) / block;
    seg_starts4_kernel<<<grid_starts, block, 0, stream>>>(
        (const int4*)ray_id, M4, M, N, ray_id, starts);

    const int n_waves = (N + RPW - 1) / RPW;
    const int grid_render = (n_waves * 64 + block - 1) / block;
    favor_render_kernel<<<grid_render, block, 0, stream>>>(
        density, rgb_feat, shift, starts, M, N,
        weights, alphainv_last, out3);
}